// Round 2
// baseline (428.310 us; speedup 1.0000x reference)
//
#include <hip/hip_runtime.h>
#include <stdint.h>

// AttentionBlock: GroupNorm(32) -> 1x1 QKV -> 8-head legacy attention -> 1x1 proj -> residual
// B=2, C=512, H=W=64 (L=4096), heads=8, ch=64.
// Pipeline: all matmuls via bf16 MFMA 16x16x32 (fp32 accum); softmax fp32; flash-style attention.

#define LTOK 4096
#define CDIM 512
#define NHEADS 8
#define EPS_GN 1e-6f
#define LOG2E 1.44269504088896f
#define QKSCALE 0.3535533905932738f   // 1/sqrt(sqrt(64))

typedef float  f4   __attribute__((ext_vector_type(4)));
typedef short  bf8  __attribute__((ext_vector_type(8)));   // 8 bf16 as shorts (guide §3 convention)
typedef unsigned short u16;
typedef unsigned short u16x8 __attribute__((ext_vector_type(8)));
typedef unsigned short u16x4 __attribute__((ext_vector_type(4)));

// T2 XOR swizzle for 128B-row LDS tiles (guide §6 G4): permutes 16B chunks within a row.
#define SWZ(row, inrow) ((inrow) ^ (((row)&7)<<4))

__device__ __forceinline__ u16 f2bf(float f){
  uint32_t u = __builtin_bit_cast(uint32_t, f);
  u += 0x7FFFu + ((u>>16)&1u);           // RNE
  return (u16)(u>>16);
}
__device__ __forceinline__ float bf2f(u16 b){
  uint32_t u = ((uint32_t)b)<<16;
  return __builtin_bit_cast(float, u);
}
// width=16 global->LDS DMA. LDS dest must be WAVE-UNIFORM (HW adds lane*16); global src is per-lane.
__device__ __forceinline__ void gload16(const void* g, void* l){
  __builtin_amdgcn_global_load_lds(
      (const __attribute__((address_space(1))) uint32_t*)g,
      (__attribute__((address_space(3))) uint32_t*)l, 16, 0, 0);
}
__device__ __forceinline__ f4 mfma16(bf8 a, bf8 b, f4 c){
  return __builtin_amdgcn_mfma_f32_16x16x32_bf16(a, b, c, 0, 0, 0);
}

// ---------------- GroupNorm ----------------
// one block per (b,g): reduce 16ch x 4096 = 65536 floats
__global__ __launch_bounds__(256) void gn_stats(const float* __restrict__ x,
                                                float* __restrict__ stats){
  const int bg = blockIdx.x;                   // b*32+g
  const float* p = x + (size_t)bg * 16 * LTOK;
  float s1 = 0.f, s2 = 0.f;
  for (int i = threadIdx.x; i < 16*LTOK/4; i += 256){
    f4 v = ((const f4*)p)[i];
    s1 += v[0]+v[1]+v[2]+v[3];
    s2 += v[0]*v[0]+v[1]*v[1]+v[2]*v[2]+v[3]*v[3];
  }
  #pragma unroll
  for (int off=32; off; off>>=1){ s1 += __shfl_down(s1, off); s2 += __shfl_down(s2, off); }
  __shared__ float a1[4], a2[4];
  const int w = threadIdx.x>>6;
  if ((threadIdx.x&63)==0){ a1[w]=s1; a2[w]=s2; }
  __syncthreads();
  if (threadIdx.x==0){
    float t1 = a1[0]+a1[1]+a1[2]+a1[3];
    float t2 = a2[0]+a2[1]+a2[2]+a2[3];
    const float inv = 1.f/(16.f*LTOK);
    float mu  = t1*inv;
    float var = t2*inv - mu*mu;
    stats[bg*2]   = mu;
    stats[bg*2+1] = rsqrtf(var + EPS_GN);
  }
}

// normalize + transpose to xnT[b][l][c] bf16 (B^T layout for the QKV GEMM)
__global__ __launch_bounds__(256) void gn_norm_t(
    const float* __restrict__ x, const float* __restrict__ gamma,
    const float* __restrict__ beta, const float* __restrict__ stats,
    u16* __restrict__ xnT){
  __shared__ float t[64][65];
  const int lb = blockIdx.x*64, cb = blockIdx.y*64, b = blockIdx.z;
  const int tid = threadIdx.x;
  {
    const int cl = tid>>4;         // 0..15
    const int ll = (tid&15)*4;     // 0..60
    #pragma unroll
    for (int rep=0; rep<4; rep++){
      const int cloc = rep*16 + cl;
      const int c = cb + cloc;
      const int grp = c>>4;                       // 16 channels/group
      const float mu = stats[(b*32+grp)*2];
      const float rs = stats[(b*32+grp)*2+1];
      const float ga = gamma[c], be = beta[c];
      f4 v = *(const f4*)(x + ((size_t)b*CDIM + c)*LTOK + lb + ll);
      t[cloc][ll+0] = (v[0]-mu)*rs*ga + be;
      t[cloc][ll+1] = (v[1]-mu)*rs*ga + be;
      t[cloc][ll+2] = (v[2]-mu)*rs*ga + be;
      t[cloc][ll+3] = (v[3]-mu)*rs*ga + be;
    }
  }
  __syncthreads();
  {
    const int l2 = tid>>2;            // 0..63
    const int c2 = (tid&3)*16;        // 0,16,32,48
    u16x8 o0, o1;
    #pragma unroll
    for (int j=0;j<8;j++){
      o0[j] = f2bf(t[c2+j][l2]);
      o1[j] = f2bf(t[c2+8+j][l2]);
    }
    u16* dst = xnT + ((size_t)b*LTOK + lb + l2)*CDIM + cb + c2;
    *(u16x8*)dst       = o0;
    *((u16x8*)dst + 1) = o1;
  }
}

// ---------------- f32 -> bf16 weight convert ----------------
__global__ __launch_bounds__(256) void cvt_bf16(const float* __restrict__ in,
                                                u16* __restrict__ out, int n4){
  int i = blockIdx.x*256 + threadIdx.x;
  if (i >= n4) return;
  f4 v = ((const f4*)in)[i];
  u16x4 o;
  o[0]=f2bf(v[0]); o[1]=f2bf(v[1]); o[2]=f2bf(v[2]); o[3]=f2bf(v[3]);
  ((u16x4*)out)[i] = o;
}

// ---------------- QKV GEMM ----------------
// D[l][o] = sum_c xnT[l][c] * W[o][c]  (A = xnT rows l, B = W rows o; both [free][k])
// epilogue: o -> head=o/192, rr=o%192; q/k scaled; writes qT/kT[bh][l][c], vT[bh][s][c]
__global__ __launch_bounds__(256) void qkv_gemm(
    const u16* __restrict__ xnT, const u16* __restrict__ wqkv,
    const float* __restrict__ bqkv,
    u16* __restrict__ qT, u16* __restrict__ kT, u16* __restrict__ vT){
  __shared__ __align__(16) char lA[16384];   // [128 l][64 k] bf16, swizzled
  __shared__ __align__(16) char lB[16384];   // [128 o][64 k] bf16, swizzled
  const int l0 = blockIdx.x*128, o0 = blockIdx.y*128, b = blockIdx.z;
  const int tid = threadIdx.x, w = tid>>6, lane = tid&63;
  const int wm = w>>1, wn = w&1, fr = lane&15, g = lane>>4;
  f4 acc[4][4] = {};
  const char* Ab = (const char*)(xnT + ((size_t)b*LTOK + l0)*CDIM);
  const char* Bb = (const char*)(wqkv + (size_t)o0*CDIM);
  for (int kt=0; kt<8; kt++){
    #pragma unroll
    for (int j=0;j<4;j++){
      const int off = w*4096 + j*1024 + lane*16;
      const int row = off>>7, inrow = off&127;
      gload16(Ab + (size_t)row*1024 + kt*128 + SWZ(row,inrow), lA + w*4096 + j*1024);
      gload16(Bb + (size_t)row*1024 + kt*128 + SWZ(row,inrow), lB + w*4096 + j*1024);
    }
    __syncthreads();
    bf8 af[4][2], bfr[4][2];
    #pragma unroll
    for (int mt=0;mt<4;mt++){
      #pragma unroll
      for (int kk=0;kk<2;kk++){
        const int row = wm*64 + mt*16 + fr;
        af[mt][kk] = *(const bf8*)(lA + row*128 + SWZ(row, kk*64 + g*16));
      }
    }
    #pragma unroll
    for (int nt=0;nt<4;nt++){
      #pragma unroll
      for (int kk=0;kk<2;kk++){
        const int row = wn*64 + nt*16 + fr;
        bfr[nt][kk] = *(const bf8*)(lB + row*128 + SWZ(row, kk*64 + g*16));
      }
    }
    #pragma unroll
    for (int mt=0;mt<4;mt++){
      #pragma unroll
      for (int nt=0;nt<4;nt++){
        acc[mt][nt] = mfma16(af[mt][0], bfr[nt][0], acc[mt][nt]);
        acc[mt][nt] = mfma16(af[mt][1], bfr[nt][1], acc[mt][nt]);
      }
    }
    __syncthreads();
  }
  // epilogue: lane holds D[l = l0+wm*64+mt*16+g*4+r][o = o0+wn*64+nt*16+fr]
  #pragma unroll
  for (int nt=0;nt<4;nt++){
    const int o = o0 + wn*64 + nt*16 + fr;
    const float bias = bqkv[o];
    const int head = o / 192;
    int rr = o - head*192;                 // legacy interleave: [q|k|v] x 64 per head
    u16* dst; float sc;
    if (rr < 64)      { dst = qT; sc = QKSCALE; }
    else if (rr < 128){ dst = kT; sc = QKSCALE; rr -= 64; }
    else              { dst = vT; sc = 1.f;     rr -= 128; }
    const size_t dbase = ((size_t)(b*NHEADS + head)*LTOK)*64 + rr;
    #pragma unroll
    for (int mt=0;mt<4;mt++){
      #pragma unroll
      for (int r=0;r<4;r++){
        const int lrow = l0 + wm*64 + mt*16 + g*4 + r;
        dst[dbase + (size_t)lrow*64] = f2bf((acc[mt][nt][r] + bias) * sc);
      }
    }
  }
}

// ---------------- flash attention ----------------
// grid (L/64, 16). 4 waves/block; wave w owns q-rows qt+w*16..+15. K/V tiles of 64.
__global__ __launch_bounds__(256) void attn(
    const u16* __restrict__ qT, const u16* __restrict__ kT,
    const u16* __restrict__ vT, u16* __restrict__ aT){
  __shared__ __align__(16) char lK[8192];      // [64 s][64 c] swizzled
  __shared__ __align__(16) char lV[8192];      // [64 c][64 s] swizzled (reg-transposed from vT)
  __shared__ __align__(16) char lP[4][2048];   // per-wave [16 t][64 s] swizzled
  const int qt = blockIdx.x*64, bh = blockIdx.y;
  const int tid = threadIdx.x, w = tid>>6, lane = tid&63;
  const int fr = lane&15, g = lane>>4;
  char* lPw = lP[w];

  bf8 qf0, qf1;                                // resident Q fragments: A[t][c]
  {
    const u16* qrow = qT + ((size_t)bh*LTOK + qt + w*16 + fr)*64;
    qf0 = *(const bf8*)(qrow + g*8);
    qf1 = *(const bf8*)(qrow + 32 + g*8);
  }
  f4 Oacc[4] = {};
  float m_r[4] = {-1e30f,-1e30f,-1e30f,-1e30f};
  float l_r[4] = {};
  const char* Kbase = (const char*)(kT + (size_t)bh*LTOK*64);
  const u16*  Vbase = vT + (size_t)bh*LTOK*64;
  const int vs0 = (tid>>3)<<1;     // 0..62 (pairs of s rows)
  const int vc0 = (tid&7)*8;       // 0..56

  for (int st=0; st<LTOK; st+=64){
    // stage K tile via direct DMA (kT already [s][c] so the tile is one linear 8KB chunk)
    #pragma unroll
    for (int j=0;j<2;j++){
      const int off = w*2048 + j*1024 + lane*16;
      const int row = off>>7, inrow = off&127;
      gload16(Kbase + (size_t)(st+row)*128 + SWZ(row,inrow), lK + w*2048 + j*1024);
    }
    // stage V tile with register transpose vT[s][c] -> lV[c][s] (pack 2 s per b32 write)
    {
      const u16* src = Vbase + (size_t)(st+vs0)*64 + vc0;
      u16x8 r0 = *(const u16x8*)src;
      u16x8 r1 = *(const u16x8*)(src + 64);
      #pragma unroll
      for (int e=0;e<8;e++){
        const uint32_t pk = (uint32_t)r0[e] | ((uint32_t)r1[e]<<16);
        const int c = vc0 + e;
        *(uint32_t*)(lV + c*128 + SWZ(c, vs0*2)) = pk;
      }
    }
    __syncthreads();

    // S = Q K^T : lane holds S[t=g*4+r][s=nt*16+fr]
    f4 Sv[4];
    #pragma unroll
    for (int nt=0;nt<4;nt++){
      const int row = nt*16 + fr;
      bf8 k0 = *(const bf8*)(lK + row*128 + SWZ(row, g*16));
      bf8 k1 = *(const bf8*)(lK + row*128 + SWZ(row, 64 + g*16));
      f4 a = {};
      a = mfma16(qf0, k0, a);
      a = mfma16(qf1, k1, a);
      Sv[nt] = a;
    }

    // online softmax per row (16-lane group reduce), write P bf16 to LDS
    float crr[4];
    #pragma unroll
    for (int r=0;r<4;r++){
      float mx = fmaxf(fmaxf(Sv[0][r],Sv[1][r]), fmaxf(Sv[2][r],Sv[3][r]));
      #pragma unroll
      for (int off=1; off<16; off<<=1) mx = fmaxf(mx, __shfl_xor(mx, off));
      const float mn = fmaxf(m_r[r], mx);
      crr[r] = exp2f((m_r[r]-mn)*LOG2E);
      m_r[r] = mn;
      const int trow = g*4 + r;
      float sum = 0.f;
      #pragma unroll
      for (int nt=0;nt<4;nt++){
        const float p = exp2f((Sv[nt][r]-mn)*LOG2E);
        const u16 pb = f2bf(p);
        sum += bf2f(pb);                     // denominator consistent with bf16 P
        *(u16*)(lPw + trow*128 + SWZ(trow, (nt*16+fr)*2)) = pb;
      }
      #pragma unroll
      for (int off=1; off<16; off<<=1) sum += __shfl_xor(sum, off);
      l_r[r] = l_r[r]*crr[r] + sum;
    }

    #pragma unroll
    for (int cn=0;cn<4;cn++){
      #pragma unroll
      for (int r=0;r<4;r++) Oacc[cn][r] *= crr[r];
    }

    // O += P V : A = P[t][s] (LDS round-trip), B = V[c][s]
    bf8 pf0 = *(const bf8*)(lPw + fr*128 + SWZ(fr, g*16));
    bf8 pf1 = *(const bf8*)(lPw + fr*128 + SWZ(fr, 64 + g*16));
    #pragma unroll
    for (int cn=0;cn<4;cn++){
      const int row = cn*16 + fr;
      bf8 v0 = *(const bf8*)(lV + row*128 + SWZ(row, g*16));
      bf8 v1 = *(const bf8*)(lV + row*128 + SWZ(row, 64 + g*16));
      Oacc[cn] = mfma16(pf0, v0, Oacc[cn]);
      Oacc[cn] = mfma16(pf1, v1, Oacc[cn]);
    }
    __syncthreads();
  }

  #pragma unroll
  for (int cn=0;cn<4;cn++){
    #pragma unroll
    for (int r=0;r<4;r++){
      const float ov = Oacc[cn][r] / l_r[r];
      const int t = qt + w*16 + g*4 + r;
      aT[((size_t)bh*LTOK + t)*64 + cn*16 + fr] = f2bf(ov);
    }
  }
}

// ---------------- proj GEMM + bias + residual ----------------
// D[o][l] = sum_c Wp[o][c] a[c][l];  a stored as aT[bh][l][c], k-tiles of 64 = one head
__global__ __launch_bounds__(256) void proj_gemm(
    const u16* __restrict__ aT, const u16* __restrict__ wp,
    const float* __restrict__ bp, const float* __restrict__ x,
    float* __restrict__ out){
  __shared__ __align__(16) char lA[16384];   // [128 o][64 c]
  __shared__ __align__(16) char lB[16384];   // [128 l][64 c]
  const int l0 = blockIdx.x*128, o0 = blockIdx.y*128, b = blockIdx.z;
  const int tid = threadIdx.x, w = tid>>6, lane = tid&63;
  const int wm = w>>1, wn = w&1, fr = lane&15, g = lane>>4;
  f4 acc[4][4] = {};
  for (int kt=0; kt<8; kt++){
    const char* Ab = (const char*)(wp + (size_t)o0*CDIM + kt*64);
    const char* Bb = (const char*)(aT + ((size_t)(b*NHEADS + kt)*LTOK + l0)*64);
    #pragma unroll
    for (int j=0;j<4;j++){
      const int off = w*4096 + j*1024 + lane*16;
      const int row = off>>7, inrow = off&127;
      gload16(Ab + (size_t)row*1024 + SWZ(row,inrow), lA + w*4096 + j*1024);
      gload16(Bb + (size_t)row*128  + SWZ(row,inrow), lB + w*4096 + j*1024);
    }
    __syncthreads();
    bf8 af[4][2], bfr[4][2];
    #pragma unroll
    for (int mt=0;mt<4;mt++){
      #pragma unroll
      for (int kk=0;kk<2;kk++){
        const int row = wm*64 + mt*16 + fr;
        af[mt][kk] = *(const bf8*)(lA + row*128 + SWZ(row, kk*64 + g*16));
      }
    }
    #pragma unroll
    for (int nt=0;nt<4;nt++){
      #pragma unroll
      for (int kk=0;kk<2;kk++){
        const int row = wn*64 + nt*16 + fr;
        bfr[nt][kk] = *(const bf8*)(lB + row*128 + SWZ(row, kk*64 + g*16));
      }
    }
    #pragma unroll
    for (int mt=0;mt<4;mt++){
      #pragma unroll
      for (int nt=0;nt<4;nt++){
        acc[mt][nt] = mfma16(af[mt][0], bfr[nt][0], acc[mt][nt]);
        acc[mt][nt] = mfma16(af[mt][1], bfr[nt][1], acc[mt][nt]);
      }
    }
    __syncthreads();
  }
  // lane holds D[o = o0+wm*64+mt*16+g*4+r][l = l0+wn*64+nt*16+fr]
  #pragma unroll
  for (int mt=0;mt<4;mt++){
    #pragma unroll
    for (int r=0;r<4;r++){
      const int o = o0 + wm*64 + mt*16 + g*4 + r;
      const float bias = bp[o];
      #pragma unroll
      for (int nt=0;nt<4;nt++){
        const int l = l0 + wn*64 + nt*16 + fr;
        const size_t idx = ((size_t)b*CDIM + o)*LTOK + l;
        out[idx] = x[idx] + bias + acc[mt][nt][r];
      }
    }
  }
}

extern "C" void kernel_launch(void* const* d_in, const int* in_sizes, int n_in,
                              void* d_out, int out_size, void* d_ws, size_t ws_size,
                              hipStream_t stream){
  const float* x     = (const float*)d_in[0];
  const float* gamma = (const float*)d_in[1];
  const float* beta  = (const float*)d_in[2];
  const float* wqkv  = (const float*)d_in[3];
  const float* bqkv  = (const float*)d_in[4];
  const float* wproj = (const float*)d_in[5];
  const float* bproj = (const float*)d_in[6];
  float* out = (float*)d_out;

  char* ws = (char*)d_ws;
  u16* xnT = (u16*)ws;  ws += (size_t)2*LTOK*CDIM*2;     // 8 MB  [b][l][c]; aT aliases this later
  u16* qT  = (u16*)ws;  ws += (size_t)16*LTOK*64*2;      // 8 MB  [bh][t][c] (pre-scaled)
  u16* kT  = (u16*)ws;  ws += (size_t)16*LTOK*64*2;      // 8 MB  [bh][s][c] (pre-scaled)
  u16* vT  = (u16*)ws;  ws += (size_t)16*LTOK*64*2;      // 8 MB  [bh][s][c]
  u16* wqb = (u16*)ws;  ws += (size_t)1536*CDIM*2;       // 1.5 MB
  u16* wpb = (u16*)ws;  ws += (size_t)CDIM*CDIM*2;       // 0.5 MB
  float* stats = (float*)ws; ws += 64*2*sizeof(float);
  u16* aT = xnT;   // alias: xnT dead after qkv_gemm, aT born in attn
  if ((size_t)(ws - (char*)d_ws) > ws_size) return;      // ws too small -> loud validation failure

  gn_stats <<<dim3(64),     dim3(256), 0, stream>>>(x, stats);
  gn_norm_t<<<dim3(64,8,2), dim3(256), 0, stream>>>(x, gamma, beta, stats, xnT);
  cvt_bf16 <<<dim3(768),    dim3(256), 0, stream>>>(wqkv,  wqb, 1536*CDIM/4);
  cvt_bf16 <<<dim3(256),    dim3(256), 0, stream>>>(wproj, wpb, CDIM*CDIM/4);
  qkv_gemm <<<dim3(32,12,2),dim3(256), 0, stream>>>(xnT, wqb, bqkv, qT, kT, vT);
  attn     <<<dim3(64,16),  dim3(256), 0, stream>>>(qT, kT, vT, aT);
  proj_gemm<<<dim3(32,4,2), dim3(256), 0, stream>>>(aT, wpb, bproj, x, out);
}

// Round 4
// 394.105 us; speedup vs baseline: 1.0868x; 1.0868x over previous
//
#include <hip/hip_runtime.h>
#include <stdint.h>

// AttentionBlock: GroupNorm(32) -> 1x1 QKV -> 8-head legacy attention -> 1x1 proj -> residual
// B=2, C=512, H=W=64 (L=4096), heads=8, ch=64.
// All matmuls via bf16 MFMA 16x16x32 (fp32 accum); softmax fp32; flash-style attention.

#define LTOK 4096
#define CDIM 512
#define NHEADS 8
#define EPS_GN 1e-6f
#define QKSCALE 0.3535533905932738f            // 1/sqrt(sqrt(64))
#define QSCL (0.3535533905932738f * 1.44269504088896f)  // LOG2E folded into q

typedef float  f4   __attribute__((ext_vector_type(4)));
typedef short  bf8  __attribute__((ext_vector_type(8)));   // 8 bf16 as shorts
typedef unsigned short u16;
typedef unsigned short u16x8 __attribute__((ext_vector_type(8)));
typedef unsigned short u16x4 __attribute__((ext_vector_type(4)));

// T2 XOR swizzle for 128B-row LDS tiles: permutes 16B chunks within a row (involution).
#define SWZ(row, inrow) ((inrow) ^ (((row)&7)<<4))

__device__ __forceinline__ u16 f2bf(float f){
  uint32_t u = __builtin_bit_cast(uint32_t, f);
  u += 0x7FFFu + ((u>>16)&1u);           // RNE
  return (u16)(u>>16);
}
__device__ __forceinline__ float bf2f(u16 b){
  uint32_t u = ((uint32_t)b)<<16;
  return __builtin_bit_cast(float, u);
}
// width=16 global->LDS DMA. LDS dest is WAVE-UNIFORM (HW adds lane*16); global src is per-lane.
__device__ __forceinline__ void gload16(const void* g, void* l){
  __builtin_amdgcn_global_load_lds(
      (const __attribute__((address_space(1))) uint32_t*)g,
      (__attribute__((address_space(3))) uint32_t*)l, 16, 0, 0);
}
__device__ __forceinline__ f4 mfma16(bf8 a, bf8 b, f4 c){
  return __builtin_amdgcn_mfma_f32_16x16x32_bf16(a, b, c, 0, 0, 0);
}
// DPP row_ror within the 16-lane row: pure-VALU cross-lane (no LDS crossbar).
template<int CTRL>
__device__ __forceinline__ float ror16(float v){
  int s = __builtin_bit_cast(int, v);
  s = __builtin_amdgcn_update_dpp(s, s, CTRL, 0xF, 0xF, true);
  return __builtin_bit_cast(float, s);
}
__device__ __forceinline__ float red16_max(float v){
  v = fmaxf(v, ror16<0x121>(v));   // ror:1
  v = fmaxf(v, ror16<0x122>(v));   // ror:2
  v = fmaxf(v, ror16<0x124>(v));   // ror:4
  v = fmaxf(v, ror16<0x128>(v));   // ror:8
  return v;
}
__device__ __forceinline__ float red16_sum(float v){
  v += ror16<0x121>(v);
  v += ror16<0x122>(v);
  v += ror16<0x124>(v);
  v += ror16<0x128>(v);
  return v;
}

// ---------------- GroupNorm ----------------
__global__ __launch_bounds__(256) void gn_stats(const float* __restrict__ x,
                                                float* __restrict__ stats){
  const int bg = blockIdx.x;                   // b*32+g
  const float* p = x + (size_t)bg * 16 * LTOK;
  float s1 = 0.f, s2 = 0.f;
  for (int i = threadIdx.x; i < 16*LTOK/4; i += 256){
    f4 v = ((const f4*)p)[i];
    s1 += v[0]+v[1]+v[2]+v[3];
    s2 += v[0]*v[0]+v[1]*v[1]+v[2]*v[2]+v[3]*v[3];
  }
  #pragma unroll
  for (int off=32; off; off>>=1){ s1 += __shfl_down(s1, off); s2 += __shfl_down(s2, off); }
  __shared__ float a1[4], a2[4];
  const int w = threadIdx.x>>6;
  if ((threadIdx.x&63)==0){ a1[w]=s1; a2[w]=s2; }
  __syncthreads();
  if (threadIdx.x==0){
    float t1 = a1[0]+a1[1]+a1[2]+a1[3];
    float t2 = a2[0]+a2[1]+a2[2]+a2[3];
    const float inv = 1.f/(16.f*LTOK);
    float mu  = t1*inv;
    float var = t2*inv - mu*mu;
    stats[bg*2]   = mu;
    stats[bg*2+1] = rsqrtf(var + EPS_GN);
  }
}

// normalize + transpose to xnT[b][l][c] bf16
__global__ __launch_bounds__(256) void gn_norm_t(
    const float* __restrict__ x, const float* __restrict__ gamma,
    const float* __restrict__ beta, const float* __restrict__ stats,
    u16* __restrict__ xnT){
  __shared__ float t[64][65];
  const int lb = blockIdx.x*64, cb = blockIdx.y*64, b = blockIdx.z;
  const int tid = threadIdx.x;
  {
    const int cl = tid>>4;         // 0..15
    const int ll = (tid&15)*4;     // 0..60
    #pragma unroll
    for (int rep=0; rep<4; rep++){
      const int cloc = rep*16 + cl;
      const int c = cb + cloc;
      const int grp = c>>4;
      const float mu = stats[(b*32+grp)*2];
      const float rs = stats[(b*32+grp)*2+1];
      const float ga = gamma[c], be = beta[c];
      f4 v = *(const f4*)(x + ((size_t)b*CDIM + c)*LTOK + lb + ll);
      t[cloc][ll+0] = (v[0]-mu)*rs*ga + be;
      t[cloc][ll+1] = (v[1]-mu)*rs*ga + be;
      t[cloc][ll+2] = (v[2]-mu)*rs*ga + be;
      t[cloc][ll+3] = (v[3]-mu)*rs*ga + be;
    }
  }
  __syncthreads();
  {
    const int l2 = tid>>2;            // 0..63
    const int c2 = (tid&3)*16;        // 0,16,32,48
    u16x8 o0, o1;
    #pragma unroll
    for (int j=0;j<8;j++){
      o0[j] = f2bf(t[c2+j][l2]);
      o1[j] = f2bf(t[c2+8+j][l2]);
    }
    u16* dst = xnT + ((size_t)b*LTOK + lb + l2)*CDIM + cb + c2;
    *(u16x8*)dst       = o0;
    *((u16x8*)dst + 1) = o1;
  }
}

// ---------------- f32 -> bf16 weight convert ----------------
__global__ __launch_bounds__(256) void cvt_bf16(const float* __restrict__ in,
                                                u16* __restrict__ out, int n4){
  int i = blockIdx.x*256 + threadIdx.x;
  if (i >= n4) return;
  f4 v = ((const f4*)in)[i];
  u16x4 o;
  o[0]=f2bf(v[0]); o[1]=f2bf(v[1]); o[2]=f2bf(v[2]); o[3]=f2bf(v[3]);
  ((u16x4*)out)[i] = o;
}

// ---------------- QKV GEMM ----------------
// D[l][o] = sum_c xnT[l][c] * W[o][c]
// epilogue: q -> qT[bh][l][c] (scaled by QSCL), k -> kT[bh][s][c] (scaled QKSCALE),
//           v -> vTt[bh][c][s]  (TRANSPOSED so attn can DMA-stage it)
__global__ __launch_bounds__(256) void qkv_gemm(
    const u16* __restrict__ xnT, const u16* __restrict__ wqkv,
    const float* __restrict__ bqkv,
    u16* __restrict__ qT, u16* __restrict__ kT, u16* __restrict__ vTt){
  __shared__ __align__(16) char lA[16384];   // [128 l][64 k] bf16, swizzled
  __shared__ __align__(16) char lB[16384];   // [128 o][64 k] bf16, swizzled
  const int l0 = blockIdx.x*128, o0 = blockIdx.y*128, b = blockIdx.z;
  const int tid = threadIdx.x, w = tid>>6, lane = tid&63;
  const int wm = w>>1, wn = w&1, fr = lane&15, g = lane>>4;
  f4 acc[4][4] = {};
  const char* Ab = (const char*)(xnT + ((size_t)b*LTOK + l0)*CDIM);
  const char* Bb = (const char*)(wqkv + (size_t)o0*CDIM);
  for (int kt=0; kt<8; kt++){
    #pragma unroll
    for (int j=0;j<4;j++){
      const int off = w*4096 + j*1024 + lane*16;
      const int row = off>>7, inrow = off&127;
      gload16(Ab + (size_t)row*1024 + kt*128 + SWZ(row,inrow), lA + w*4096 + j*1024);
      gload16(Bb + (size_t)row*1024 + kt*128 + SWZ(row,inrow), lB + w*4096 + j*1024);
    }
    __syncthreads();
    bf8 af[4][2], bfr[4][2];
    #pragma unroll
    for (int mt=0;mt<4;mt++){
      #pragma unroll
      for (int kk=0;kk<2;kk++){
        const int row = wm*64 + mt*16 + fr;
        af[mt][kk] = *(const bf8*)(lA + row*128 + SWZ(row, kk*64 + g*16));
      }
    }
    #pragma unroll
    for (int nt=0;nt<4;nt++){
      #pragma unroll
      for (int kk=0;kk<2;kk++){
        const int row = wn*64 + nt*16 + fr;
        bfr[nt][kk] = *(const bf8*)(lB + row*128 + SWZ(row, kk*64 + g*16));
      }
    }
    #pragma unroll
    for (int mt=0;mt<4;mt++){
      #pragma unroll
      for (int nt=0;nt<4;nt++){
        acc[mt][nt] = mfma16(af[mt][0], bfr[nt][0], acc[mt][nt]);
        acc[mt][nt] = mfma16(af[mt][1], bfr[nt][1], acc[mt][nt]);
      }
    }
    __syncthreads();
  }
  // lane holds D[l = l0+wm*64+mt*16+g*4+r][o = o0+wn*64+nt*16+fr]
  #pragma unroll
  for (int nt=0;nt<4;nt++){
    const int o = o0 + wn*64 + nt*16 + fr;
    const float bias = bqkv[o];
    const int head = o / 192;
    int rr = o - head*192;                 // legacy interleave: [q|k|v] x 64 per head
    const int lbase = l0 + wm*64 + g*4;
    if (rr < 128){
      u16* dst; float sc;
      if (rr < 64){ dst = qT; sc = QSCL; }
      else        { dst = kT; sc = QKSCALE; rr -= 64; }
      const size_t dbase = ((size_t)(b*NHEADS + head)*LTOK)*64 + rr;
      #pragma unroll
      for (int mt=0;mt<4;mt++){
        #pragma unroll
        for (int r=0;r<4;r++)
          dst[dbase + (size_t)(lbase + mt*16 + r)*64] = f2bf((acc[mt][nt][r] + bias) * sc);
      }
    } else {
      rr -= 128;
      u16* dst = vTt + ((size_t)(b*NHEADS + head)*64 + rr)*LTOK;
      #pragma unroll
      for (int mt=0;mt<4;mt++){
        u16x4 pk;
        #pragma unroll
        for (int r=0;r<4;r++) pk[r] = f2bf(acc[mt][nt][r] + bias);
        *(u16x4*)(dst + lbase + mt*16) = pk;   // 4 consecutive s -> 8B store
      }
    }
  }
}

// ---------------- flash attention ----------------
// 1D grid of 1024; decode keeps each head-pair on one XCD (K/V L2-resident).
// 4 waves/block; wave w owns q-rows qt+w*16..+15. K/V tiles of 64.
__global__ __launch_bounds__(256) void attn(
    const u16* __restrict__ qT, const u16* __restrict__ kT,
    const u16* __restrict__ vTt, u16* __restrict__ aT){
  __shared__ __align__(16) char lK[8192];      // [64 s][64 c] swizzled
  __shared__ __align__(16) char lV[8192];      // [64 c][64 s] swizzled (DMA from vTt)
  __shared__ __align__(16) char lP[4][2048];   // per-wave [16 t][64 s] swizzled
  const int bid = blockIdx.x;
  const int bh = (bid&7) | (((bid>>3)&1)<<3);  // XCD-pinned head pair
  const int qt = (bid>>4)*64;
  const int tid = threadIdx.x, w = tid>>6, lane = tid&63;
  const int fr = lane&15, g = lane>>4;
  char* lPw = lP[w];

  bf8 qf0, qf1;                                // resident Q fragments: A[t][c]
  {
    const u16* qrow = qT + ((size_t)bh*LTOK + qt + w*16 + fr)*64;
    qf0 = *(const bf8*)(qrow + g*8);
    qf1 = *(const bf8*)(qrow + 32 + g*8);
  }
  f4 Oacc[4] = {};
  float m_r[4] = {-1e30f,-1e30f,-1e30f,-1e30f};
  float l_r[4] = {};
  const char* Kbase = (const char*)(kT  + (size_t)bh*LTOK*64);
  const char* Vbase = (const char*)(vTt + (size_t)bh*64*LTOK);

  for (int st=0; st<LTOK; st+=64){
    // stage K [s][c] and V^T [c][s] tiles via direct DMA (both linear-dest, src pre-swizzled)
    #pragma unroll
    for (int j=0;j<2;j++){
      const int off = w*2048 + j*1024 + lane*16;
      const int row = off>>7, inrow = off&127;
      gload16(Kbase + (size_t)(st+row)*128 + SWZ(row,inrow), lK + w*2048 + j*1024);
      gload16(Vbase + (size_t)row*8192 + st*2 + SWZ(row,inrow), lV + w*2048 + j*1024);
    }
    __syncthreads();

    // S = Q K^T : lane holds S[t=g*4+r][s=nt*16+fr]  (log2-scaled: LOG2E folded into q)
    f4 Sv[4];
    #pragma unroll
    for (int nt=0;nt<4;nt++){
      const int row = nt*16 + fr;
      bf8 k0 = *(const bf8*)(lK + row*128 + SWZ(row, g*16));
      bf8 k1 = *(const bf8*)(lK + row*128 + SWZ(row, 64 + g*16));
      f4 a = {};
      a = mfma16(qf0, k0, a);
      a = mfma16(qf1, k1, a);
      Sv[nt] = a;
    }

    // online softmax per row: DPP row_ror reductions (no LDS crossbar), exp2 direct
    float crr[4];
    #pragma unroll
    for (int r=0;r<4;r++){
      float mx = fmaxf(fmaxf(Sv[0][r],Sv[1][r]), fmaxf(Sv[2][r],Sv[3][r]));
      mx = red16_max(mx);
      const float mn = fmaxf(m_r[r], mx);
      crr[r] = exp2f(m_r[r]-mn);
      m_r[r] = mn;
      const int trow = g*4 + r;
      float sum = 0.f;
      #pragma unroll
      for (int nt=0;nt<4;nt++){
        const float p = exp2f(Sv[nt][r]-mn);
        const u16 pb = f2bf(p);
        sum += bf2f(pb);                     // denominator consistent with bf16 P
        *(u16*)(lPw + trow*128 + SWZ(trow, (nt*16+fr)*2)) = pb;
      }
      sum = red16_sum(sum);
      l_r[r] = l_r[r]*crr[r] + sum;
    }

    #pragma unroll
    for (int cn=0;cn<4;cn++){
      #pragma unroll
      for (int r=0;r<4;r++) Oacc[cn][r] *= crr[r];
    }

    // O += P V : A = P[t][s] (LDS round-trip), B = V[c][s]
    bf8 pf0 = *(const bf8*)(lPw + fr*128 + SWZ(fr, g*16));
    bf8 pf1 = *(const bf8*)(lPw + fr*128 + SWZ(fr, 64 + g*16));
    #pragma unroll
    for (int cn=0;cn<4;cn++){
      const int row = cn*16 + fr;
      bf8 v0 = *(const bf8*)(lV + row*128 + SWZ(row, g*16));
      bf8 v1 = *(const bf8*)(lV + row*128 + SWZ(row, 64 + g*16));
      Oacc[cn] = mfma16(pf0, v0, Oacc[cn]);
      Oacc[cn] = mfma16(pf1, v1, Oacc[cn]);
    }
    __syncthreads();
  }

  #pragma unroll
  for (int cn=0;cn<4;cn++){
    #pragma unroll
    for (int r=0;r<4;r++){
      const float ov = Oacc[cn][r] / l_r[r];
      const int t = qt + w*16 + g*4 + r;
      aT[((size_t)bh*LTOK + t)*64 + cn*16 + fr] = f2bf(ov);
    }
  }
}

// ---------------- proj GEMM + bias + residual ----------------
__global__ __launch_bounds__(256) void proj_gemm(
    const u16* __restrict__ aT, const u16* __restrict__ wp,
    const float* __restrict__ bp, const float* __restrict__ x,
    float* __restrict__ out){
  __shared__ __align__(16) char lA[16384];   // [128 o][64 c]
  __shared__ __align__(16) char lB[16384];   // [128 l][64 c]
  const int l0 = blockIdx.x*128, o0 = blockIdx.y*128, b = blockIdx.z;
  const int tid = threadIdx.x, w = tid>>6, lane = tid&63;
  const int wm = w>>1, wn = w&1, fr = lane&15, g = lane>>4;
  f4 acc[4][4] = {};
  for (int kt=0; kt<8; kt++){
    const char* Ab = (const char*)(wp + (size_t)o0*CDIM + kt*64);
    const char* Bb = (const char*)(aT + ((size_t)(b*NHEADS + kt)*LTOK + l0)*64);
    #pragma unroll
    for (int j=0;j<4;j++){
      const int off = w*4096 + j*1024 + lane*16;
      const int row = off>>7, inrow = off&127;
      gload16(Ab + (size_t)row*1024 + SWZ(row,inrow), lA + w*4096 + j*1024);
      gload16(Bb + (size_t)row*128  + SWZ(row,inrow), lB + w*4096 + j*1024);
    }
    __syncthreads();
    bf8 af[4][2], bfr[4][2];
    #pragma unroll
    for (int mt=0;mt<4;mt++){
      #pragma unroll
      for (int kk=0;kk<2;kk++){
        const int row = wm*64 + mt*16 + fr;
        af[mt][kk] = *(const bf8*)(lA + row*128 + SWZ(row, kk*64 + g*16));
      }
    }
    #pragma unroll
    for (int nt=0;nt<4;nt++){
      #pragma unroll
      for (int kk=0;kk<2;kk++){
        const int row = wn*64 + nt*16 + fr;
        bfr[nt][kk] = *(const bf8*)(lB + row*128 + SWZ(row, kk*64 + g*16));
      }
    }
    #pragma unroll
    for (int mt=0;mt<4;mt++){
      #pragma unroll
      for (int nt=0;nt<4;nt++){
        acc[mt][nt] = mfma16(af[mt][0], bfr[nt][0], acc[mt][nt]);
        acc[mt][nt] = mfma16(af[mt][1], bfr[nt][1], acc[mt][nt]);
      }
    }
    __syncthreads();
  }
  // lane holds D[o = o0+wm*64+mt*16+g*4+r][l = l0+wn*64+nt*16+fr]
  #pragma unroll
  for (int mt=0;mt<4;mt++){
    #pragma unroll
    for (int r=0;r<4;r++){
      const int o = o0 + wm*64 + mt*16 + g*4 + r;
      const float bias = bp[o];
      #pragma unroll
      for (int nt=0;nt<4;nt++){
        const int l = l0 + wn*64 + nt*16 + fr;
        const size_t idx = ((size_t)b*CDIM + o)*LTOK + l;
        out[idx] = x[idx] + bias + acc[mt][nt][r];
      }
    }
  }
}

extern "C" void kernel_launch(void* const* d_in, const int* in_sizes, int n_in,
                              void* d_out, int out_size, void* d_ws, size_t ws_size,
                              hipStream_t stream){
  const float* x     = (const float*)d_in[0];
  const float* gamma = (const float*)d_in[1];
  const float* beta  = (const float*)d_in[2];
  const float* wqkv  = (const float*)d_in[3];
  const float* bqkv  = (const float*)d_in[4];
  const float* wproj = (const float*)d_in[5];
  const float* bproj = (const float*)d_in[6];
  float* out = (float*)d_out;

  char* ws = (char*)d_ws;
  u16* xnT = (u16*)ws;  ws += (size_t)2*LTOK*CDIM*2;     // 8 MB  [b][l][c]; aT aliases this later
  u16* qT  = (u16*)ws;  ws += (size_t)16*LTOK*64*2;      // 8 MB  [bh][t][c] (pre-scaled, LOG2E folded)
  u16* kT  = (u16*)ws;  ws += (size_t)16*LTOK*64*2;      // 8 MB  [bh][s][c] (pre-scaled)
  u16* vTt = (u16*)ws;  ws += (size_t)16*LTOK*64*2;      // 8 MB  [bh][c][s] (TRANSPOSED)
  u16* wqb = (u16*)ws;  ws += (size_t)1536*CDIM*2;       // 1.5 MB
  u16* wpb = (u16*)ws;  ws += (size_t)CDIM*CDIM*2;       // 0.5 MB
  float* stats = (float*)ws; ws += 64*2*sizeof(float);
  u16* aT = xnT;   // alias: xnT dead after qkv_gemm, aT born in attn
  if ((size_t)(ws - (char*)d_ws) > ws_size) return;      // ws too small -> loud validation failure

  gn_stats <<<dim3(64),     dim3(256), 0, stream>>>(x, stats);
  gn_norm_t<<<dim3(64,8,2), dim3(256), 0, stream>>>(x, gamma, beta, stats, xnT);
  cvt_bf16 <<<dim3(768),    dim3(256), 0, stream>>>(wqkv,  wqb, 1536*CDIM/4);
  cvt_bf16 <<<dim3(256),    dim3(256), 0, stream>>>(wproj, wpb, CDIM*CDIM/4);
  qkv_gemm <<<dim3(32,12,2),dim3(256), 0, stream>>>(xnT, wqb, bqkv, qT, kT, vTt);
  attn     <<<dim3(1024),   dim3(256), 0, stream>>>(qT, kT, vTt, aT);
  proj_gemm<<<dim3(32,4,2), dim3(256), 0, stream>>>(aT, wpb, bproj, x, out);
}

// Round 6
// 379.860 us; speedup vs baseline: 1.1275x; 1.0375x over previous
//
#include <hip/hip_runtime.h>
#include <stdint.h>

// AttentionBlock: GroupNorm(32) -> 1x1 QKV -> 8-head legacy attention -> 1x1 proj -> residual
// B=2, C=512, H=W=64 (L=4096), heads=8, ch=64.
// attn v2: swapped 32x32x16 MFMA flash attention, all-register softmax, no LDS.

#define LTOK 4096
#define CDIM 512
#define NHEADS 8
#define EPS_GN 1e-6f
#define QKSCALE 0.3535533905932738f            // 1/sqrt(sqrt(64))
#define QSCL (0.3535533905932738f * 1.44269504088896f)  // LOG2E folded into q

typedef float  f4   __attribute__((ext_vector_type(4)));
typedef float  f16v __attribute__((ext_vector_type(16)));
typedef short  bf8  __attribute__((ext_vector_type(8)));   // 8 bf16 as shorts
typedef unsigned short u16;
typedef unsigned short u16x8 __attribute__((ext_vector_type(8)));
typedef unsigned short u16x4 __attribute__((ext_vector_type(4)));
typedef uint32_t u32;
typedef uint32_t u32x2 __attribute__((ext_vector_type(2)));
typedef uint32_t u32x4 __attribute__((ext_vector_type(4)));

// T2 XOR swizzle for 128B-row LDS tiles (GEMM kernels): involution on 16B chunks.
#define SWZ(row, inrow) ((inrow) ^ (((row)&7)<<4))

__device__ __forceinline__ u16 f2bf(float f){
  uint32_t u = __builtin_bit_cast(uint32_t, f);
  u += 0x7FFFu + ((u>>16)&1u);           // RNE
  return (u16)(u>>16);
}
// width=16 global->LDS DMA (GEMM staging). LDS dest wave-uniform; global src per-lane.
__device__ __forceinline__ void gload16(const void* g, void* l){
  __builtin_amdgcn_global_load_lds(
      (const __attribute__((address_space(1))) uint32_t*)g,
      (__attribute__((address_space(3))) uint32_t*)l, 16, 0, 0);
}
__device__ __forceinline__ f4 mfma16(bf8 a, bf8 b, f4 c){
  return __builtin_amdgcn_mfma_f32_16x16x32_bf16(a, b, c, 0, 0, 0);
}
__device__ __forceinline__ f16v mfma32(bf8 a, bf8 b, f16v c){
  return __builtin_amdgcn_mfma_f32_32x32x16_bf16(a, b, c, 0, 0, 0);
}
__device__ __forceinline__ u32 cvtpk(float a, float b){
  u32 d;
  asm("v_cvt_pk_bf16_f32 %0, %1, %2" : "=v"(d) : "v"(a), "v"(b));
  return d;
}

// ---------------- GroupNorm ----------------
__global__ __launch_bounds__(256) void gn_stats(const float* __restrict__ x,
                                                float* __restrict__ stats){
  const int bg = blockIdx.x;                   // b*32+g
  const float* p = x + (size_t)bg * 16 * LTOK;
  float s1 = 0.f, s2 = 0.f;
  for (int i = threadIdx.x; i < 16*LTOK/4; i += 256){
    f4 v = ((const f4*)p)[i];
    s1 += v[0]+v[1]+v[2]+v[3];
    s2 += v[0]*v[0]+v[1]*v[1]+v[2]*v[2]+v[3]*v[3];
  }
  #pragma unroll
  for (int off=32; off; off>>=1){ s1 += __shfl_down(s1, off); s2 += __shfl_down(s2, off); }
  __shared__ float a1[4], a2[4];
  const int w = threadIdx.x>>6;
  if ((threadIdx.x&63)==0){ a1[w]=s1; a2[w]=s2; }
  __syncthreads();
  if (threadIdx.x==0){
    float t1 = a1[0]+a1[1]+a1[2]+a1[3];
    float t2 = a2[0]+a2[1]+a2[2]+a2[3];
    const float inv = 1.f/(16.f*LTOK);
    float mu  = t1*inv;
    float var = t2*inv - mu*mu;
    stats[bg*2]   = mu;
    stats[bg*2+1] = rsqrtf(var + EPS_GN);
  }
}

// normalize + transpose to xnT[b][l][c] bf16
__global__ __launch_bounds__(256) void gn_norm_t(
    const float* __restrict__ x, const float* __restrict__ gamma,
    const float* __restrict__ beta, const float* __restrict__ stats,
    u16* __restrict__ xnT){
  __shared__ float t[64][65];
  const int lb = blockIdx.x*64, cb = blockIdx.y*64, b = blockIdx.z;
  const int tid = threadIdx.x;
  {
    const int cl = tid>>4;         // 0..15
    const int ll = (tid&15)*4;     // 0..60
    #pragma unroll
    for (int rep=0; rep<4; rep++){
      const int cloc = rep*16 + cl;
      const int c = cb + cloc;
      const int grp = c>>4;
      const float mu = stats[(b*32+grp)*2];
      const float rs = stats[(b*32+grp)*2+1];
      const float ga = gamma[c], be = beta[c];
      f4 v = *(const f4*)(x + ((size_t)b*CDIM + c)*LTOK + lb + ll);
      t[cloc][ll+0] = (v[0]-mu)*rs*ga + be;
      t[cloc][ll+1] = (v[1]-mu)*rs*ga + be;
      t[cloc][ll+2] = (v[2]-mu)*rs*ga + be;
      t[cloc][ll+3] = (v[3]-mu)*rs*ga + be;
    }
  }
  __syncthreads();
  {
    const int l2 = tid>>2;            // 0..63
    const int c2 = (tid&3)*16;        // 0,16,32,48
    u16x8 o0, o1;
    #pragma unroll
    for (int j=0;j<8;j++){
      o0[j] = f2bf(t[c2+j][l2]);
      o1[j] = f2bf(t[c2+8+j][l2]);
    }
    u16* dst = xnT + ((size_t)b*LTOK + lb + l2)*CDIM + cb + c2;
    *(u16x8*)dst       = o0;
    *((u16x8*)dst + 1) = o1;
  }
}

// ---------------- f32 -> bf16 weight convert ----------------
__global__ __launch_bounds__(256) void cvt_bf16(const float* __restrict__ in,
                                                u16* __restrict__ out, int n4){
  int i = blockIdx.x*256 + threadIdx.x;
  if (i >= n4) return;
  f4 v = ((const f4*)in)[i];
  u16x4 o;
  o[0]=f2bf(v[0]); o[1]=f2bf(v[1]); o[2]=f2bf(v[2]); o[3]=f2bf(v[3]);
  ((u16x4*)out)[i] = o;
}

// ---------------- QKV GEMM ----------------
// D[l][o] = sum_c xnT[l][c] * W[o][c]
// epilogue: q -> qT[bh][l][c] (scaled QSCL), k -> kT[bh][s][c] (scaled QKSCALE),
//           v -> vTt[bh][c][s] (transposed)
__global__ __launch_bounds__(256) void qkv_gemm(
    const u16* __restrict__ xnT, const u16* __restrict__ wqkv,
    const float* __restrict__ bqkv,
    u16* __restrict__ qT, u16* __restrict__ kT, u16* __restrict__ vTt){
  __shared__ __align__(16) char lA[16384];   // [128 l][64 k] bf16, swizzled
  __shared__ __align__(16) char lB[16384];   // [128 o][64 k] bf16, swizzled
  const int l0 = blockIdx.x*128, o0 = blockIdx.y*128, b = blockIdx.z;
  const int tid = threadIdx.x, w = tid>>6, lane = tid&63;
  const int wm = w>>1, wn = w&1, fr = lane&15, g = lane>>4;
  f4 acc[4][4] = {};
  const char* Ab = (const char*)(xnT + ((size_t)b*LTOK + l0)*CDIM);
  const char* Bb = (const char*)(wqkv + (size_t)o0*CDIM);
  for (int kt=0; kt<8; kt++){
    #pragma unroll
    for (int j=0;j<4;j++){
      const int off = w*4096 + j*1024 + lane*16;
      const int row = off>>7, inrow = off&127;
      gload16(Ab + (size_t)row*1024 + kt*128 + SWZ(row,inrow), lA + w*4096 + j*1024);
      gload16(Bb + (size_t)row*1024 + kt*128 + SWZ(row,inrow), lB + w*4096 + j*1024);
    }
    __syncthreads();
    bf8 af[4][2], bfr[4][2];
    #pragma unroll
    for (int mt=0;mt<4;mt++){
      #pragma unroll
      for (int kk=0;kk<2;kk++){
        const int row = wm*64 + mt*16 + fr;
        af[mt][kk] = *(const bf8*)(lA + row*128 + SWZ(row, kk*64 + g*16));
      }
    }
    #pragma unroll
    for (int nt=0;nt<4;nt++){
      #pragma unroll
      for (int kk=0;kk<2;kk++){
        const int row = wn*64 + nt*16 + fr;
        bfr[nt][kk] = *(const bf8*)(lB + row*128 + SWZ(row, kk*64 + g*16));
      }
    }
    #pragma unroll
    for (int mt=0;mt<4;mt++){
      #pragma unroll
      for (int nt=0;nt<4;nt++){
        acc[mt][nt] = mfma16(af[mt][0], bfr[nt][0], acc[mt][nt]);
        acc[mt][nt] = mfma16(af[mt][1], bfr[nt][1], acc[mt][nt]);
      }
    }
    __syncthreads();
  }
  // lane holds D[l = l0+wm*64+mt*16+g*4+r][o = o0+wn*64+nt*16+fr]
  #pragma unroll
  for (int nt=0;nt<4;nt++){
    const int o = o0 + wn*64 + nt*16 + fr;
    const float bias = bqkv[o];
    const int head = o / 192;
    int rr = o - head*192;                 // legacy interleave: [q|k|v] x 64 per head
    const int lbase = l0 + wm*64 + g*4;
    if (rr < 128){
      u16* dst; float sc;
      if (rr < 64){ dst = qT; sc = QSCL; }
      else        { dst = kT; sc = QKSCALE; rr -= 64; }
      const size_t dbase = ((size_t)(b*NHEADS + head)*LTOK)*64 + rr;
      #pragma unroll
      for (int mt=0;mt<4;mt++){
        #pragma unroll
        for (int r=0;r<4;r++)
          dst[dbase + (size_t)(lbase + mt*16 + r)*64] = f2bf((acc[mt][nt][r] + bias) * sc);
      }
    } else {
      rr -= 128;
      u16* dst = vTt + ((size_t)(b*NHEADS + head)*64 + rr)*LTOK;
      #pragma unroll
      for (int mt=0;mt<4;mt++){
        u16x4 pk;
        #pragma unroll
        for (int r=0;r<4;r++) pk[r] = f2bf(acc[mt][nt][r] + bias);
        *(u16x4*)(dst + lbase + mt*16) = pk;   // 4 consecutive s -> 8B store
      }
    }
  }
}

// ---------------- flash attention v2 (swapped 32x32 MFMA, no LDS) ----------------
// Swapped QK^T: S^T = mfma(A=K, B=Q)  ->  lane owns ONE q-column t=lane&31;
// s spans regs: s = (reg&3) + 8*(reg>>2) + 4*(lane>>5). m/l are per-lane scalars.
// P -> bf16 via v_cvt_pk_bf16_f32, lane-half exchange via shfl_xor(32)+select
// builds PV B-fragments in-register. K/V fragments load straight from global (L2).

__device__ __forceinline__ void loadK(const u16* kp, int s, bf8 k0[4], bf8 k1[4]){
  const u16* p = kp + (size_t)s*64;
  #pragma unroll
  for (int sl=0; sl<4; sl++){
    k0[sl] = *(const bf8*)(p + 16*sl);          // rows s..s+31
    k1[sl] = *(const bf8*)(p + 2048 + 16*sl);   // rows s+32..s+63
  }
}
__device__ __forceinline__ void loadV(const u16* vp, int s, bf8 v0[4], bf8 v1[4]){
  const u16* p = vp + s;
  #pragma unroll
  for (int ks=0; ks<4; ks++){
    v0[ks] = *(const bf8*)(p + 16*ks);              // c rows 0..31
    v1[ks] = *(const bf8*)(p + 32*LTOK + 16*ks);    // c rows 32..63
  }
}
// Build one PV B-fragment (k-slice of 16 s) from 4 packed u32 (P pairs).
__device__ __forceinline__ bf8 pfrag(u32 a0, u32 a1, u32 a2, u32 a3, bool hb){
  u32 x0 = (u32)__shfl_xor((int)a2, 32);
  u32 x1 = (u32)__shfl_xor((int)a3, 32);
  u32 x2 = (u32)__shfl_xor((int)a0, 32);
  u32 x3 = (u32)__shfl_xor((int)a1, 32);
  u32x4 w;
  w[0] = hb ? x0 : a0;
  w[1] = hb ? x1 : a1;
  w[2] = hb ? a2 : x2;
  w[3] = hb ? a3 : x3;
  return __builtin_bit_cast(bf8, w);
}

__device__ __forceinline__ void attn_tile(
    const bf8 k0[4], const bf8 k1[4], const bf8 v0[4], const bf8 v1[4],
    const bf8 q[4], f16v& acc0, f16v& acc1, float& m, float& lsum, bool hb){
  f16v SA = {}, SB = {};
  #pragma unroll
  for (int sl=0; sl<4; sl++){
    SA = mfma32(k0[sl], q[sl], SA);   // s-subtile 0..31
    SB = mfma32(k1[sl], q[sl], SB);   // s-subtile 32..63
  }
  // row max (t is lane-local): reg tree + cross-half shfl
  float t8[8];
  #pragma unroll
  for (int i=0;i<8;i++)
    t8[i] = fmaxf(fmaxf(SA[2*i],SA[2*i+1]), fmaxf(SB[2*i],SB[2*i+1]));
  float mx = fmaxf(fmaxf(fmaxf(t8[0],t8[1]), fmaxf(t8[2],t8[3])),
                   fmaxf(fmaxf(t8[4],t8[5]), fmaxf(t8[6],t8[7])));
  mx = fmaxf(mx, __shfl_xor(mx, 32));
  const float mn = fmaxf(m, mx);
  const float crr = exp2f(m - mn);
  m = mn;
  #pragma unroll
  for (int i=0;i<16;i++){ SA[i] = exp2f(SA[i]-mn); SB[i] = exp2f(SB[i]-mn); }
  float s8[8];
  #pragma unroll
  for (int i=0;i<8;i++)
    s8[i] = (SA[2*i]+SA[2*i+1]) + (SB[2*i]+SB[2*i+1]);
  float ts = ((s8[0]+s8[1])+(s8[2]+s8[3])) + ((s8[4]+s8[5])+(s8[6]+s8[7]));
  ts += __shfl_xor(ts, 32);
  lsum = lsum*crr + ts;
  #pragma unroll
  for (int i=0;i<16;i++){ acc0[i] *= crr; acc1[i] *= crr; }
  // pack P to bf16 pairs (adjacent s): PA[p] = (s=4h+..), see frag derivation
  u32 PA[8], PB[8];
  #pragma unroll
  for (int p=0;p<8;p++){
    PA[p] = cvtpk(SA[2*p], SA[2*p+1]);
    PB[p] = cvtpk(SB[2*p], SB[2*p+1]);
  }
  bf8 pf0 = pfrag(PA[0],PA[1],PA[2],PA[3], hb);   // s 0..15
  bf8 pf1 = pfrag(PA[4],PA[5],PA[6],PA[7], hb);   // s 16..31
  bf8 pf2 = pfrag(PB[0],PB[1],PB[2],PB[3], hb);   // s 32..47
  bf8 pf3 = pfrag(PB[4],PB[5],PB[6],PB[7], hb);   // s 48..63
  acc0 = mfma32(v0[0], pf0, acc0);  acc1 = mfma32(v1[0], pf0, acc1);
  acc0 = mfma32(v0[1], pf1, acc0);  acc1 = mfma32(v1[1], pf1, acc1);
  acc0 = mfma32(v0[2], pf2, acc0);  acc1 = mfma32(v1[2], pf2, acc1);
  acc0 = mfma32(v0[3], pf3, acc0);  acc1 = mfma32(v1[3], pf3, acc1);
}

__global__ __launch_bounds__(256,2) void attn2(
    const u16* __restrict__ qT, const u16* __restrict__ kT,
    const u16* __restrict__ vTt, u16* __restrict__ aT){
  const int bid = blockIdx.x;                   // 512 blocks
  const int j = bid >> 3;                       // 0..63
  const int bh = (bid&7)*2 + (j&1);             // 2 heads per XCD
  const int tb = (j>>1)*128 + ((threadIdx.x>>6)<<5);
  const int lane = threadIdx.x & 63, r = lane & 31;
  const bool hb = (lane >> 5) != 0;
  const int h8 = (lane>>5)*8;

  bf8 q[4];
  const u16* qp = qT + ((size_t)bh*LTOK + tb + r)*64 + h8;
  #pragma unroll
  for (int sl=0; sl<4; sl++) q[sl] = *(const bf8*)(qp + 16*sl);

  const u16* kp = kT  + (size_t)bh*LTOK*64 + (size_t)r*64 + h8;
  const u16* vp = vTt + ((size_t)bh*64 + r)*LTOK + h8;

  f16v acc0 = {}, acc1 = {};
  float m = -3e38f, lsum = 0.f;

  bf8 kA0[4],kA1[4], kB0[4],kB1[4], v0[4],v1[4];
  loadK(kp, 0, kA0, kA1);
  for (int s0=0; s0<LTOK; s0+=128){
    loadV(vp, s0, v0, v1);
    loadK(kp, s0+64, kB0, kB1);                       // prefetch tile B
    attn_tile(kA0,kA1, v0,v1, q, acc0,acc1, m,lsum, hb);
    loadV(vp, s0+64, v0, v1);
    const int sn = (s0+128 < LTOK) ? s0+128 : 0;      // clamped prefetch tile A'
    loadK(kp, sn, kA0, kA1);
    attn_tile(kB0,kB1, v0,v1, q, acc0,acc1, m,lsum, hb);
  }

  const float inv = 1.f/lsum;
  u16* op = aT + ((size_t)bh*LTOK + tb + r)*64;
  #pragma unroll
  for (int qd=0; qd<4; qd++){
    u32x2 w0, w1;
    w0[0] = cvtpk(acc0[4*qd]*inv,   acc0[4*qd+1]*inv);
    w0[1] = cvtpk(acc0[4*qd+2]*inv, acc0[4*qd+3]*inv);
    *(u32x2*)(op + 8*qd + (hb?4:0)) = w0;             // c = 8qd+4h+{0..3}
    w1[0] = cvtpk(acc1[4*qd]*inv,   acc1[4*qd+1]*inv);
    w1[1] = cvtpk(acc1[4*qd+2]*inv, acc1[4*qd+3]*inv);
    *(u32x2*)(op + 32 + 8*qd + (hb?4:0)) = w1;        // c = 32+8qd+4h+{0..3}
  }
}

// ---------------- proj GEMM + bias + residual ----------------
__global__ __launch_bounds__(256) void proj_gemm(
    const u16* __restrict__ aT, const u16* __restrict__ wp,
    const float* __restrict__ bp, const float* __restrict__ x,
    float* __restrict__ out){
  __shared__ __align__(16) char lA[16384];   // [128 o][64 c]
  __shared__ __align__(16) char lB[16384];   // [128 l][64 c]
  const int l0 = blockIdx.x*128, o0 = blockIdx.y*128, b = blockIdx.z;
  const int tid = threadIdx.x, w = tid>>6, lane = tid&63;
  const int wm = w>>1, wn = w&1, fr = lane&15, g = lane>>4;
  f4 acc[4][4] = {};
  for (int kt=0; kt<8; kt++){
    const char* Ab = (const char*)(wp + (size_t)o0*CDIM + kt*64);
    const char* Bb = (const char*)(aT + ((size_t)(b*NHEADS + kt)*LTOK + l0)*64);
    #pragma unroll
    for (int j=0;j<4;j++){
      const int off = w*4096 + j*1024 + lane*16;
      const int row = off>>7, inrow = off&127;
      gload16(Ab + (size_t)row*1024 + SWZ(row,inrow), lA + w*4096 + j*1024);
      gload16(Bb + (size_t)row*128  + SWZ(row,inrow), lB + w*4096 + j*1024);
    }
    __syncthreads();
    bf8 af[4][2], bfr[4][2];
    #pragma unroll
    for (int mt=0;mt<4;mt++){
      #pragma unroll
      for (int kk=0;kk<2;kk++){
        const int row = wm*64 + mt*16 + fr;
        af[mt][kk] = *(const bf8*)(lA + row*128 + SWZ(row, kk*64 + g*16));
      }
    }
    #pragma unroll
    for (int nt=0;nt<4;nt++){
      #pragma unroll
      for (int kk=0;kk<2;kk++){
        const int row = wn*64 + nt*16 + fr;
        bfr[nt][kk] = *(const bf8*)(lB + row*128 + SWZ(row, kk*64 + g*16));
      }
    }
    #pragma unroll
    for (int mt=0;mt<4;mt++){
      #pragma unroll
      for (int nt=0;nt<4;nt++){
        acc[mt][nt] = mfma16(af[mt][0], bfr[nt][0], acc[mt][nt]);
        acc[mt][nt] = mfma16(af[mt][1], bfr[nt][1], acc[mt][nt]);
      }
    }
    __syncthreads();
  }
  // lane holds D[o = o0+wm*64+mt*16+g*4+r][l = l0+wn*64+nt*16+fr]
  #pragma unroll
  for (int mt=0;mt<4;mt++){
    #pragma unroll
    for (int r=0;r<4;r++){
      const int o = o0 + wm*64 + mt*16 + g*4 + r;
      const float bias = bp[o];
      #pragma unroll
      for (int nt=0;nt<4;nt++){
        const int l = l0 + wn*64 + nt*16 + fr;
        const size_t idx = ((size_t)b*CDIM + o)*LTOK + l;
        out[idx] = x[idx] + bias + acc[mt][nt][r];
      }
    }
  }
}

extern "C" void kernel_launch(void* const* d_in, const int* in_sizes, int n_in,
                              void* d_out, int out_size, void* d_ws, size_t ws_size,
                              hipStream_t stream){
  const float* x     = (const float*)d_in[0];
  const float* gamma = (const float*)d_in[1];
  const float* beta  = (const float*)d_in[2];
  const float* wqkv  = (const float*)d_in[3];
  const float* bqkv  = (const float*)d_in[4];
  const float* wproj = (const float*)d_in[5];
  const float* bproj = (const float*)d_in[6];
  float* out = (float*)d_out;

  char* ws = (char*)d_ws;
  u16* xnT = (u16*)ws;  ws += (size_t)2*LTOK*CDIM*2;     // 8 MB  [b][l][c]; aT aliases this later
  u16* qT  = (u16*)ws;  ws += (size_t)16*LTOK*64*2;      // 8 MB  [bh][t][c] (pre-scaled, LOG2E folded)
  u16* kT  = (u16*)ws;  ws += (size_t)16*LTOK*64*2;      // 8 MB  [bh][s][c] (pre-scaled)
  u16* vTt = (u16*)ws;  ws += (size_t)16*LTOK*64*2;      // 8 MB  [bh][c][s] (transposed)
  u16* wqb = (u16*)ws;  ws += (size_t)1536*CDIM*2;       // 1.5 MB
  u16* wpb = (u16*)ws;  ws += (size_t)CDIM*CDIM*2;       // 0.5 MB
  float* stats = (float*)ws; ws += 64*2*sizeof(float);
  u16* aT = xnT;   // alias: xnT dead after qkv_gemm, aT born in attn
  if ((size_t)(ws - (char*)d_ws) > ws_size) return;      // ws too small -> loud validation failure

  gn_stats <<<dim3(64),     dim3(256), 0, stream>>>(x, stats);
  gn_norm_t<<<dim3(64,8,2), dim3(256), 0, stream>>>(x, gamma, beta, stats, xnT);
  cvt_bf16 <<<dim3(768),    dim3(256), 0, stream>>>(wqkv,  wqb, 1536*CDIM/4);
  cvt_bf16 <<<dim3(256),    dim3(256), 0, stream>>>(wproj, wpb, CDIM*CDIM/4);
  qkv_gemm <<<dim3(32,12,2),dim3(256), 0, stream>>>(xnT, wqb, bqkv, qT, kT, vTt);
  attn2    <<<dim3(512),    dim3(256), 0, stream>>>(qT, kT, vTt, aT);
  proj_gemm<<<dim3(32,4,2), dim3(256), 0, stream>>>(aT, wpb, bproj, x, out);
}

// Round 10
// 266.417 us; speedup vs baseline: 1.6077x; 1.4258x over previous
//
#include <hip/hip_runtime.h>
#include <stdint.h>

// AttentionBlock: GroupNorm(32) -> 1x1 QKV -> 8-head legacy attention -> 1x1 proj -> residual
// B=2, C=512, H=W=64 (L=4096), heads=8, ch=64.
// attn v4: swapped 32x32x16 MFMA flash attention; Q/K/V stored in FRAGMENT ORDER by the
// QKV GEMM epilogue so every attention load is a coalesced 1KB dwordx4 (no LDS, no barriers).
// P-assembly and cross-half reductions use HW-VERIFIED shfl_xor forms (round-6 validated);
// permlane32_swap removed pending semantics verification (round-8 failure post-mortem).

#define LTOK 4096
#define CDIM 512
#define NHEADS 8
#define EPS_GN 1e-6f
#define QKSCALE 0.3535533905932738f            // 1/sqrt(sqrt(64))
#define QSCL (0.3535533905932738f * 1.44269504088896f)  // LOG2E folded into q
#define FRAG_BH 262144                          // elems per bh in qF/kF/vF (=4096*64)

typedef float  f4   __attribute__((ext_vector_type(4)));
typedef float  f16v __attribute__((ext_vector_type(16)));
typedef short  bf8  __attribute__((ext_vector_type(8)));   // 8 bf16 as shorts
typedef unsigned short u16;
typedef unsigned short u16x8 __attribute__((ext_vector_type(8)));
typedef unsigned short u16x4 __attribute__((ext_vector_type(4)));
typedef uint32_t u32;
typedef uint32_t u32x2 __attribute__((ext_vector_type(2)));
typedef uint32_t u32x4 __attribute__((ext_vector_type(4)));

// T2 XOR swizzle for 128B-row LDS tiles (GEMM kernels): involution on 16B chunks.
#define SWZ(row, inrow) ((inrow) ^ (((row)&7)<<4))

__device__ __forceinline__ u16 f2bf(float f){
  uint32_t u = __builtin_bit_cast(uint32_t, f);
  u += 0x7FFFu + ((u>>16)&1u);           // RNE
  return (u16)(u>>16);
}
// width=16 global->LDS DMA (GEMM staging). LDS dest wave-uniform; global src per-lane.
__device__ __forceinline__ void gload16(const void* g, void* l){
  __builtin_amdgcn_global_load_lds(
      (const __attribute__((address_space(1))) uint32_t*)g,
      (__attribute__((address_space(3))) uint32_t*)l, 16, 0, 0);
}
__device__ __forceinline__ f4 mfma16(bf8 a, bf8 b, f4 c){
  return __builtin_amdgcn_mfma_f32_16x16x32_bf16(a, b, c, 0, 0, 0);
}
__device__ __forceinline__ f16v mfma32(bf8 a, bf8 b, f16v c){
  return __builtin_amdgcn_mfma_f32_32x32x16_bf16(a, b, c, 0, 0, 0);
}
__device__ __forceinline__ u32 cvtpk(float a, float b){
  u32 d;
  asm("v_cvt_pk_bf16_f32 %0, %1, %2" : "=v"(d) : "v"(a), "v"(b));
  return d;
}

// ---------------- GroupNorm ----------------
__global__ __launch_bounds__(256) void gn_stats(const float* __restrict__ x,
                                                float* __restrict__ stats){
  const int bg = blockIdx.x;                   // b*32+g
  const float* p = x + (size_t)bg * 16 * LTOK;
  float s1 = 0.f, s2 = 0.f;
  for (int i = threadIdx.x; i < 16*LTOK/4; i += 256){
    f4 v = ((const f4*)p)[i];
    s1 += v[0]+v[1]+v[2]+v[3];
    s2 += v[0]*v[0]+v[1]*v[1]+v[2]*v[2]+v[3]*v[3];
  }
  #pragma unroll
  for (int off=32; off; off>>=1){ s1 += __shfl_down(s1, off); s2 += __shfl_down(s2, off); }
  __shared__ float a1[4], a2[4];
  const int w = threadIdx.x>>6;
  if ((threadIdx.x&63)==0){ a1[w]=s1; a2[w]=s2; }
  __syncthreads();
  if (threadIdx.x==0){
    float t1 = a1[0]+a1[1]+a1[2]+a1[3];
    float t2 = a2[0]+a2[1]+a2[2]+a2[3];
    const float inv = 1.f/(16.f*LTOK);
    float mu  = t1*inv;
    float var = t2*inv - mu*mu;
    stats[bg*2]   = mu;
    stats[bg*2+1] = rsqrtf(var + EPS_GN);
  }
}

// normalize + transpose to xnT[b][l][c] bf16
__global__ __launch_bounds__(256) void gn_norm_t(
    const float* __restrict__ x, const float* __restrict__ gamma,
    const float* __restrict__ beta, const float* __restrict__ stats,
    u16* __restrict__ xnT){
  __shared__ float t[64][65];
  const int lb = blockIdx.x*64, cb = blockIdx.y*64, b = blockIdx.z;
  const int tid = threadIdx.x;
  {
    const int cl = tid>>4;         // 0..15
    const int ll = (tid&15)*4;     // 0..60
    #pragma unroll
    for (int rep=0; rep<4; rep++){
      const int cloc = rep*16 + cl;
      const int c = cb + cloc;
      const int grp = c>>4;
      const float mu = stats[(b*32+grp)*2];
      const float rs = stats[(b*32+grp)*2+1];
      const float ga = gamma[c], be = beta[c];
      f4 v = *(const f4*)(x + ((size_t)b*CDIM + c)*LTOK + lb + ll);
      t[cloc][ll+0] = (v[0]-mu)*rs*ga + be;
      t[cloc][ll+1] = (v[1]-mu)*rs*ga + be;
      t[cloc][ll+2] = (v[2]-mu)*rs*ga + be;
      t[cloc][ll+3] = (v[3]-mu)*rs*ga + be;
    }
  }
  __syncthreads();
  {
    const int l2 = tid>>2;            // 0..63
    const int c2 = (tid&3)*16;        // 0,16,32,48
    u16x8 o0, o1;
    #pragma unroll
    for (int j=0;j<8;j++){
      o0[j] = f2bf(t[c2+j][l2]);
      o1[j] = f2bf(t[c2+8+j][l2]);
    }
    u16* dst = xnT + ((size_t)b*LTOK + lb + l2)*CDIM + cb + c2;
    *(u16x8*)dst       = o0;
    *((u16x8*)dst + 1) = o1;
  }
}

// ---------------- f32 -> bf16 weight convert ----------------
__global__ __launch_bounds__(256) void cvt_bf16(const float* __restrict__ in,
                                                u16* __restrict__ out, int n4){
  int i = blockIdx.x*256 + threadIdx.x;
  if (i >= n4) return;
  f4 v = ((const f4*)in)[i];
  u16x4 o;
  o[0]=f2bf(v[0]); o[1]=f2bf(v[1]); o[2]=f2bf(v[2]); o[3]=f2bf(v[3]);
  ((u16x4*)out)[i] = o;
}

// ---------------- QKV GEMM ----------------
// D[l][o] = sum_c xnT[l][c] * W[o][c]
// epilogue writes FRAGMENT-ORDER q/k/v:
//   qF/kF[bh]: elem = ((tile32*4 + sl)*2 + h)*256 + row*8 + j   (t=tile32*32+row, c=16sl+8h+j)
//   vF[bh]:    elem = ((tile64*4 + ks)*2 + h)*512 + c*8 + j     (s=tile64*64+16ks+8h+j)
__global__ __launch_bounds__(256) void qkv_gemm(
    const u16* __restrict__ xnT, const u16* __restrict__ wqkv,
    const float* __restrict__ bqkv,
    u16* __restrict__ qF, u16* __restrict__ kF, u16* __restrict__ vF){
  __shared__ __align__(16) char lA[16384];   // [128 l][64 k] bf16, swizzled
  __shared__ __align__(16) char lB[16384];   // [128 o][64 k] bf16, swizzled
  const int l0 = blockIdx.x*128, o0 = blockIdx.y*128, b = blockIdx.z;
  const int tid = threadIdx.x, w = tid>>6, lane = tid&63;
  const int wm = w>>1, wn = w&1, fr = lane&15, g = lane>>4;
  f4 acc[4][4] = {};
  const char* Ab = (const char*)(xnT + ((size_t)b*LTOK + l0)*CDIM);
  const char* Bb = (const char*)(wqkv + (size_t)o0*CDIM);
  for (int kt=0; kt<8; kt++){
    #pragma unroll
    for (int j=0;j<4;j++){
      const int off = w*4096 + j*1024 + lane*16;
      const int row = off>>7, inrow = off&127;
      gload16(Ab + (size_t)row*1024 + kt*128 + SWZ(row,inrow), lA + w*4096 + j*1024);
      gload16(Bb + (size_t)row*1024 + kt*128 + SWZ(row,inrow), lB + w*4096 + j*1024);
    }
    __syncthreads();
    bf8 af[4][2], bfr[4][2];
    #pragma unroll
    for (int mt=0;mt<4;mt++){
      #pragma unroll
      for (int kk=0;kk<2;kk++){
        const int row = wm*64 + mt*16 + fr;
        af[mt][kk] = *(const bf8*)(lA + row*128 + SWZ(row, kk*64 + g*16));
      }
    }
    #pragma unroll
    for (int nt=0;nt<4;nt++){
      #pragma unroll
      for (int kk=0;kk<2;kk++){
        const int row = wn*64 + nt*16 + fr;
        bfr[nt][kk] = *(const bf8*)(lB + row*128 + SWZ(row, kk*64 + g*16));
      }
    }
    #pragma unroll
    for (int mt=0;mt<4;mt++){
      #pragma unroll
      for (int nt=0;nt<4;nt++){
        acc[mt][nt] = mfma16(af[mt][0], bfr[nt][0], acc[mt][nt]);
        acc[mt][nt] = mfma16(af[mt][1], bfr[nt][1], acc[mt][nt]);
      }
    }
    __syncthreads();
  }
  // lane holds D[l = l0+wm*64+mt*16+g*4+r_][o = o0+wn*64+nt*16+fr]
  #pragma unroll
  for (int nt=0;nt<4;nt++){
    const int o = o0 + wn*64 + nt*16 + fr;
    const float bias = bqkv[o];
    const int head = o / 192;
    int rr = o - head*192;                 // legacy interleave: [q|k|v] x 64 per head
    const int bh = b*NHEADS + head;
    if (rr < 128){
      u16* base; float sc;
      if (rr < 64){ base = qF; sc = QSCL; }
      else        { base = kF; sc = QKSCALE; rr -= 64; }
      const int sl = rr>>4, hq = (rr>>3)&1, j = rr&7;
      const int Tb = (l0 + wm*64)>>5;                  // tile32 base
      u16* p = base + (size_t)bh*FRAG_BH + (size_t)(sl*2 + hq)*256 + j;
      #pragma unroll
      for (int mt=0;mt<4;mt++){
        const size_t toff = (size_t)(Tb + (mt>>1))*2048 + (size_t)((mt&1)*16 + g*4)*8;
        #pragma unroll
        for (int r_=0;r_<4;r_++)
          p[toff + r_*8] = f2bf((acc[mt][nt][r_] + bias) * sc);
      }
    } else {
      rr -= 128;                                       // rr = c
      const int s64 = (l0>>6) + wm;
      u16* p = vF + (size_t)bh*FRAG_BH + (size_t)s64*4096 + (size_t)(g>>1)*512
                  + (size_t)rr*8 + (g&1)*4;
      #pragma unroll
      for (int mt=0;mt<4;mt++){                        // ks = mt
        u16x4 pk;
        #pragma unroll
        for (int r_=0;r_<4;r_++) pk[r_] = f2bf(acc[mt][nt][r_] + bias);
        *(u16x4*)(p + mt*1024) = pk;
      }
    }
  }
}

// ---------------- flash attention v4 ----------------
__device__ __forceinline__ void loadKF(const u16* kl, int t64, bf8 k0[4], bf8 k1[4]){
  const u16* p = kl + (size_t)t64*4096;
  #pragma unroll
  for (int sl=0; sl<4; sl++){
    k0[sl] = *(const bf8*)(p + sl*512);           // s rows t64*64 + r
    k1[sl] = *(const bf8*)(p + 2048 + sl*512);    // s rows +32
  }
}
__device__ __forceinline__ void loadVF(const u16* vl, int t64, bf8 v0[4], bf8 v1[4]){
  const u16* p = vl + (size_t)t64*4096;
  #pragma unroll
  for (int ks=0; ks<4; ks++){
    v0[ks] = *(const bf8*)(p + ks*1024);          // c rows 0..31
    v1[ks] = *(const bf8*)(p + ks*1024 + 256);    // c rows 32..63
  }
}
// Build one PV B-fragment (k-slice of 16 s) from 4 packed u32 (P pairs).
// HW-VERIFIED form (round 6 passed validation with this exact structure).
__device__ __forceinline__ bf8 pfrag(u32 a0, u32 a1, u32 a2, u32 a3, bool hb){
  u32 x0 = (u32)__shfl_xor((int)a2, 32);
  u32 x1 = (u32)__shfl_xor((int)a3, 32);
  u32 x2 = (u32)__shfl_xor((int)a0, 32);
  u32 x3 = (u32)__shfl_xor((int)a1, 32);
  u32x4 w;
  w[0] = hb ? x0 : a0;
  w[1] = hb ? x1 : a1;
  w[2] = hb ? a2 : x2;
  w[3] = hb ? a3 : x3;
  return __builtin_bit_cast(bf8, w);
}

__device__ __forceinline__ void attn_tile(
    const bf8 k0[4], const bf8 k1[4], const bf8 v0[4], const bf8 v1[4],
    const bf8 q[4], f16v& acc0, f16v& acc1, float& m, float& lsum, bool hb){
  f16v SA = {}, SB = {};
  #pragma unroll
  for (int sl=0; sl<4; sl++){
    SA = mfma32(k0[sl], q[sl], SA);   // s-subtile 0..31
    SB = mfma32(k1[sl], q[sl], SB);   // s-subtile 32..63
  }
  float t8[8];
  #pragma unroll
  for (int i=0;i<8;i++)
    t8[i] = fmaxf(fmaxf(SA[2*i],SA[2*i+1]), fmaxf(SB[2*i],SB[2*i+1]));
  float mx = fmaxf(fmaxf(fmaxf(t8[0],t8[1]), fmaxf(t8[2],t8[3])),
                   fmaxf(fmaxf(t8[4],t8[5]), fmaxf(t8[6],t8[7])));
  mx = fmaxf(mx, __shfl_xor(mx, 32));
  // defer-max (T13): only rescale when the running max grew by > 8 (P bounded by 2^8)
  if (!__all(mx <= m + 8.f)){
    const float mn = fmaxf(m, mx);
    const float crr = exp2f(m - mn);
    m = mn; lsum *= crr;
    #pragma unroll
    for (int i=0;i<16;i++){ acc0[i] *= crr; acc1[i] *= crr; }
  }
  #pragma unroll
  for (int i=0;i<16;i++){ SA[i] = exp2f(SA[i]-m); SB[i] = exp2f(SB[i]-m); }
  float s8[8];
  #pragma unroll
  for (int i=0;i<8;i++)
    s8[i] = (SA[2*i]+SA[2*i+1]) + (SB[2*i]+SB[2*i+1]);
  float ts = ((s8[0]+s8[1])+(s8[2]+s8[3])) + ((s8[4]+s8[5])+(s8[6]+s8[7]));
  ts += __shfl_xor(ts, 32);
  lsum += ts;
  // P -> bf16 pairs; cross-half exchange via verified shfl_xor pfrag
  u32 PA[8], PB[8];
  #pragma unroll
  for (int p=0;p<8;p++){
    PA[p] = cvtpk(SA[2*p], SA[2*p+1]);
    PB[p] = cvtpk(SB[2*p], SB[2*p+1]);
  }
  const bf8 pf0 = pfrag(PA[0],PA[1],PA[2],PA[3], hb);   // s 0..15
  const bf8 pf1 = pfrag(PA[4],PA[5],PA[6],PA[7], hb);   // s 16..31
  const bf8 pf2 = pfrag(PB[0],PB[1],PB[2],PB[3], hb);   // s 32..47
  const bf8 pf3 = pfrag(PB[4],PB[5],PB[6],PB[7], hb);   // s 48..63
  acc0 = mfma32(v0[0], pf0, acc0);  acc1 = mfma32(v1[0], pf0, acc1);
  acc0 = mfma32(v0[1], pf1, acc0);  acc1 = mfma32(v1[1], pf1, acc1);
  acc0 = mfma32(v0[2], pf2, acc0);  acc1 = mfma32(v1[2], pf2, acc1);
  acc0 = mfma32(v0[3], pf3, acc0);  acc1 = mfma32(v1[3], pf3, acc1);
}

__global__ __launch_bounds__(256,2) void attn4(
    const u16* __restrict__ qF, const u16* __restrict__ kF,
    const u16* __restrict__ vF, u16* __restrict__ aT){
  const int bid = blockIdx.x;                   // 512 blocks
  const int bh = (bid&7)*2 + ((bid>>3)&1);      // XCD-pinned head pair
  const int qt = (bid>>4)*128 + ((threadIdx.x>>6)<<5);
  const int lane = threadIdx.x & 63, r = lane & 31, h = lane>>5;
  const bool hb = h != 0;

  bf8 q[4];
  const u16* qb = qF + (size_t)bh*FRAG_BH + (size_t)(qt>>5)*2048 + h*256 + r*8;
  #pragma unroll
  for (int sl=0; sl<4; sl++) q[sl] = *(const bf8*)(qb + sl*512);

  const u16* kl = kF + (size_t)bh*FRAG_BH + h*256 + r*8;
  const u16* vl = vF + (size_t)bh*FRAG_BH + h*512 + r*8;

  f16v acc0 = {}, acc1 = {};
  float m = -3e38f, lsum = 0.f;

  bf8 kA0[4],kA1[4], kB0[4],kB1[4], v0[4],v1[4];
  loadKF(kl, 0, kA0, kA1);
  for (int t=0; t<64; t+=2){
    loadVF(vl, t, v0, v1);
    loadKF(kl, t+1, kB0, kB1);                    // prefetch K tile B
    attn_tile(kA0,kA1, v0,v1, q, acc0,acc1, m,lsum, hb);
    loadVF(vl, t+1, v0, v1);
    const int nx = (t+2 < 64) ? t+2 : 0;          // clamped prefetch A'
    loadKF(kl, nx, kA0, kA1);
    attn_tile(kB0,kB1, v0,v1, q, acc0,acc1, m,lsum, hb);
  }

  const float inv = 1.f/lsum;
  u16* op = aT + ((size_t)bh*LTOK + qt + r)*64;
  #pragma unroll
  for (int qd=0; qd<4; qd++){
    u32x2 w0, w1;
    w0[0] = cvtpk(acc0[4*qd]*inv,   acc0[4*qd+1]*inv);
    w0[1] = cvtpk(acc0[4*qd+2]*inv, acc0[4*qd+3]*inv);
    *(u32x2*)(op + 8*qd + (h?4:0)) = w0;          // c = 8qd+4h+{0..3}
    w1[0] = cvtpk(acc1[4*qd]*inv,   acc1[4*qd+1]*inv);
    w1[1] = cvtpk(acc1[4*qd+2]*inv, acc1[4*qd+3]*inv);
    *(u32x2*)(op + 32 + 8*qd + (h?4:0)) = w1;     // c = 32+8qd+4h+{0..3}
  }
}

// ---------------- proj GEMM + bias + residual ----------------
__global__ __launch_bounds__(256) void proj_gemm(
    const u16* __restrict__ aT, const u16* __restrict__ wp,
    const float* __restrict__ bp, const float* __restrict__ x,
    float* __restrict__ out){
  __shared__ __align__(16) char lA[16384];   // [128 o][64 c]
  __shared__ __align__(16) char lB[16384];   // [128 l][64 c]
  const int l0 = blockIdx.x*128, o0 = blockIdx.y*128, b = blockIdx.z;
  const int tid = threadIdx.x, w = tid>>6, lane = tid&63;
  const int wm = w>>1, wn = w&1, fr = lane&15, g = lane>>4;
  f4 acc[4][4] = {};
  for (int kt=0; kt<8; kt++){
    const char* Ab = (const char*)(wp + (size_t)o0*CDIM + kt*64);
    const char* Bb = (const char*)(aT + ((size_t)(b*NHEADS + kt)*LTOK + l0)*64);
    #pragma unroll
    for (int j=0;j<4;j++){
      const int off = w*4096 + j*1024 + lane*16;
      const int row = off>>7, inrow = off&127;
      gload16(Ab + (size_t)row*1024 + SWZ(row,inrow), lA + w*4096 + j*1024);
      gload16(Bb + (size_t)row*128  + SWZ(row,inrow), lB + w*4096 + j*1024);
    }
    __syncthreads();
    bf8 af[4][2], bfr[4][2];
    #pragma unroll
    for (int mt=0;mt<4;mt++){
      #pragma unroll
      for (int kk=0;kk<2;kk++){
        const int row = wm*64 + mt*16 + fr;
        af[mt][kk] = *(const bf8*)(lA + row*128 + SWZ(row, kk*64 + g*16));
      }
    }
    #pragma unroll
    for (int nt=0;nt<4;nt++){
      #pragma unroll
      for (int kk=0;kk<2;kk++){
        const int row = wn*64 + nt*16 + fr;
        bfr[nt][kk] = *(const bf8*)(lB + row*128 + SWZ(row, kk*64 + g*16));
      }
    }
    #pragma unroll
    for (int mt=0;mt<4;mt++){
      #pragma unroll
      for (int nt=0;nt<4;nt++){
        acc[mt][nt] = mfma16(af[mt][0], bfr[nt][0], acc[mt][nt]);
        acc[mt][nt] = mfma16(af[mt][1], bfr[nt][1], acc[mt][nt]);
      }
    }
    __syncthreads();
  }
  // lane holds D[o = o0+wm*64+mt*16+g*4+r][l = l0+wn*64+nt*16+fr]
  #pragma unroll
  for (int mt=0;mt<4;mt++){
    #pragma unroll
    for (int r=0;r<4;r++){
      const int o = o0 + wm*64 + mt*16 + g*4 + r;
      const float bias = bp[o];
      #pragma unroll
      for (int nt=0;nt<4;nt++){
        const int l = l0 + wn*64 + nt*16 + fr;
        const size_t idx = ((size_t)b*CDIM + o)*LTOK + l;
        out[idx] = x[idx] + bias + acc[mt][nt][r];
      }
    }
  }
}

extern "C" void kernel_launch(void* const* d_in, const int* in_sizes, int n_in,
                              void* d_out, int out_size, void* d_ws, size_t ws_size,
                              hipStream_t stream){
  const float* x     = (const float*)d_in[0];
  const float* gamma = (const float*)d_in[1];
  const float* beta  = (const float*)d_in[2];
  const float* wqkv  = (const float*)d_in[3];
  const float* bqkv  = (const float*)d_in[4];
  const float* wproj = (const float*)d_in[5];
  const float* bproj = (const float*)d_in[6];
  float* out = (float*)d_out;

  char* ws = (char*)d_ws;
  u16* xnT = (u16*)ws;  ws += (size_t)2*LTOK*CDIM*2;     // 8 MB  [b][l][c]; aT aliases this later
  u16* qF  = (u16*)ws;  ws += (size_t)16*FRAG_BH*2;      // 8 MB  fragment-order Q (pre-scaled)
  u16* kF  = (u16*)ws;  ws += (size_t)16*FRAG_BH*2;      // 8 MB  fragment-order K (pre-scaled)
  u16* vF  = (u16*)ws;  ws += (size_t)16*FRAG_BH*2;      // 8 MB  fragment-order V
  u16* wqb = (u16*)ws;  ws += (size_t)1536*CDIM*2;       // 1.5 MB
  u16* wpb = (u16*)ws;  ws += (size_t)CDIM*CDIM*2;       // 0.5 MB
  float* stats = (float*)ws; ws += 64*2*sizeof(float);
  u16* aT = xnT;   // alias: xnT dead after qkv_gemm, aT born in attn
  if ((size_t)(ws - (char*)d_ws) > ws_size) return;      // ws too small -> loud validation failure

  gn_stats <<<dim3(64),     dim3(256), 0, stream>>>(x, stats);
  gn_norm_t<<<dim3(64,8,2), dim3(256), 0, stream>>>(x, gamma, beta, stats, xnT);
  cvt_bf16 <<<dim3(768),    dim3(256), 0, stream>>>(wqkv,  wqb, 1536*CDIM/4);
  cvt_bf16 <<<dim3(256),    dim3(256), 0, stream>>>(wproj, wpb, CDIM*CDIM/4);
  qkv_gemm <<<dim3(32,12,2),dim3(256), 0, stream>>>(xnT, wqb, bqkv, qF, kF, vF);
  attn4    <<<dim3(512),    dim3(256), 0, stream>>>(qF, kF, vF, aT);
  proj_gemm<<<dim3(32,4,2), dim3(256), 0, stream>>>(aT, wpb, bproj, x, out);
}